// Round 1
// baseline (13963.365 us; speedup 1.0000x reference)
//
#include <hip/hip_runtime.h>

#define B_ 64
#define T_ 512
#define I_ 512
#define H_ 1024
#define HN (B_ * H_)   // 65536 elements per h buffer
#define FPAD 16        // flags padded to 64B lines
#define G_ 64          // recurrence workgroups

typedef __attribute__((ext_vector_type(8))) short bf16x8;
typedef __attribute__((ext_vector_type(4))) float f32x4;

static __device__ __forceinline__ short f2bf(float f) {
  unsigned u = __float_as_uint(f);
  unsigned r = (u + 0x7fffu + ((u >> 16) & 1u)) >> 16;  // RNE
  return (short)(unsigned short)r;
}
static __device__ __forceinline__ float bf2f(short s) {
  return __uint_as_float(((unsigned)(unsigned short)s) << 16);
}
static __device__ __forceinline__ bf16x8 pack8(float4 u, float4 v) {
  bf16x8 r;
  r[0] = f2bf(u.x); r[1] = f2bf(u.y); r[2] = f2bf(u.z); r[3] = f2bf(u.w);
  r[4] = f2bf(v.x); r[5] = f2bf(v.y); r[6] = f2bf(v.z); r[7] = f2bf(v.w);
  return r;
}

// ---------------------------------------------------------------------------
// Kernel 1: pre = x @ Wi^T + bi + bh, written IN-PLACE into d_out[b*T*H + t*H + n]
// (row m = b*T + t of x maps directly to out offset m*H). 128x128 tile, BK=32.
// ---------------------------------------------------------------------------
#define PBK 32
#define PLDA 40  // padded row stride (shorts); 80B = 16B-aligned rows

__global__ __launch_bounds__(256) void proj_gemm(
    const float* __restrict__ x, const float* __restrict__ Wi,
    const float* __restrict__ bi, const float* __restrict__ bh,
    float* __restrict__ out) {
  __shared__ short As[128 * PLDA];
  __shared__ short Bs[128 * PLDA];
  const int tid = threadIdx.x;
  const int m0 = (blockIdx.x >> 3) * 128;
  const int n0 = (blockIdx.x & 7) * 128;
  const int wave = tid >> 6, lane = tid & 63;
  const int wm = (wave & 1) * 64, wn = (wave >> 1) * 64;
  const int lm = lane & 15, lq = lane >> 4;

  f32x4 acc[4][4];
#pragma unroll
  for (int i = 0; i < 4; ++i)
#pragma unroll
    for (int j = 0; j < 4; ++j) {
      f32x4 z = {0.f, 0.f, 0.f, 0.f};
      acc[i][j] = z;
    }

  const int lrow = tid >> 1;
  const int lcol = (tid & 1) * 16;
  const float* xp = x + (size_t)(m0 + lrow) * I_ + lcol;
  const float* wp = Wi + (size_t)(n0 + lrow) * I_ + lcol;

  for (int k0 = 0; k0 < I_; k0 += PBK) {
    float4 a0 = *(const float4*)(xp + k0);
    float4 a1 = *(const float4*)(xp + k0 + 4);
    float4 a2 = *(const float4*)(xp + k0 + 8);
    float4 a3 = *(const float4*)(xp + k0 + 12);
    float4 b0 = *(const float4*)(wp + k0);
    float4 b1 = *(const float4*)(wp + k0 + 4);
    float4 b2 = *(const float4*)(wp + k0 + 8);
    float4 b3 = *(const float4*)(wp + k0 + 12);
    __syncthreads();  // previous iter's LDS reads done
    *(bf16x8*)&As[lrow * PLDA + lcol] = pack8(a0, a1);
    *(bf16x8*)&As[lrow * PLDA + lcol + 8] = pack8(a2, a3);
    *(bf16x8*)&Bs[lrow * PLDA + lcol] = pack8(b0, b1);
    *(bf16x8*)&Bs[lrow * PLDA + lcol + 8] = pack8(b2, b3);
    __syncthreads();

    bf16x8 af[4], bfr[4];
#pragma unroll
    for (int i = 0; i < 4; ++i)
      af[i] = *(const bf16x8*)&As[(wm + i * 16 + lm) * PLDA + lq * 8];
#pragma unroll
    for (int j = 0; j < 4; ++j)
      bfr[j] = *(const bf16x8*)&Bs[(wn + j * 16 + lm) * PLDA + lq * 8];
#pragma unroll
    for (int i = 0; i < 4; ++i)
#pragma unroll
      for (int j = 0; j < 4; ++j)
        acc[i][j] = __builtin_amdgcn_mfma_f32_16x16x32_bf16(af[i], bfr[j],
                                                            acc[i][j], 0, 0, 0);
  }

  const int rb = m0 + wm + lq * 4;
  const int cb = n0 + wn + lm;
#pragma unroll
  for (int j = 0; j < 4; ++j) {
    const int n = cb + j * 16;
    const float bias = bi[n] + bh[n];
#pragma unroll
    for (int i = 0; i < 4; ++i) {
      const int m = rb + i * 16;
#pragma unroll
      for (int r = 0; r < 4; ++r)
        out[(size_t)(m + r) * H_ + n] = acc[i][j][r] + bias;
    }
  }
}

// ---------------------------------------------------------------------------
// Device-scope barrier among G_ persistent workgroups (padded flags in ws).
// ws is poisoned 0xAA each launch -> initial flag value is negative, so
// "wait until >= val" with val = 1,2,... is safe without initialization.
// ---------------------------------------------------------------------------
static __device__ __forceinline__ void grid_barrier(int* flags, int bid,
                                                    int tid, int val) {
  __threadfence();   // release own h/out stores device-wide
  __syncthreads();   // all threads of WG past their fences
  if (tid == 0)
    __hip_atomic_store(&flags[bid * FPAD], val, __ATOMIC_RELEASE,
                       __HIP_MEMORY_SCOPE_AGENT);
  const int f = (tid & 63) * FPAD;  // every thread polls one flag (2x coverage)
  while (__hip_atomic_load(&flags[f], __ATOMIC_RELAXED,
                           __HIP_MEMORY_SCOPE_AGENT) < val) {}
  __syncthreads();
  __threadfence();   // acquire before reading remote h
}

// ---------------------------------------------------------------------------
// Kernel 2: persistent recurrence. G_=64 WGs x 128 threads (2 waves).
// WG g owns output cols [16g,16g+16). Wh slice split hi/lo bf16 in LDS,
// pre-swizzled to MFMA B-frag order. h ping-pongs in ws as bf16 hi/lo.
// 3-term bf16x3 product: hi*Whi + hi*Wlo + lo*Whi (error ~2e-5/step).
// pre is read from d_out and overwritten in place with h_t.
// ---------------------------------------------------------------------------
__global__ __launch_bounds__(128) void rnn_rec(const float* __restrict__ Wh,
                                               float* __restrict__ out,
                                               short* __restrict__ hbuf,
                                               int* __restrict__ flags) {
  __shared__ short BhiS[32 * 64 * 8];  // 32 KB
  __shared__ short BloS[32 * 64 * 8];  // 32 KB
  const int tid = threadIdx.x;
  const int g = blockIdx.x;
  const int n0 = g * 16;
  const int wv = tid >> 6;  // 0..1
  const int lane = tid & 63;
  const int lm = lane & 15, lq = lane >> 4;

  // Stage Wh cols slice, split into hi/lo, swizzled into exact B-frag order:
  // frag element j of lane l for K-block kb sits at [(kb*64+l)*8 + j].
  for (int idx = tid; idx < 32 * 64; idx += 128) {
    const int kb = idx >> 6, l = idx & 63;
    const int n = n0 + (l & 15);
    const int k = kb * 32 + ((l >> 4) & 3) * 8;
    const float* p = Wh + (size_t)n * H_ + k;
    float4 w0 = *(const float4*)p;
    float4 w1 = *(const float4*)(p + 4);
    float wf[8] = {w0.x, w0.y, w0.z, w0.w, w1.x, w1.y, w1.z, w1.w};
#pragma unroll
    for (int j = 0; j < 8; ++j) {
      const short h = f2bf(wf[j]);
      BhiS[idx * 8 + j] = h;
      BloS[idx * 8 + j] = f2bf(wf[j] - bf2f(h));
    }
  }

  // zero-init h0 slice (this WG's columns) in ping buffer 0 (hi and lo)
  for (int idx = tid; idx < B_ * 16; idx += 128) {
    const int row = idx >> 4, col = n0 + (idx & 15);
    hbuf[row * H_ + col] = 0;             // Hhi buf0
    hbuf[2 * HN + row * H_ + col] = 0;    // Hlo buf0
  }

  grid_barrier(flags, g, tid, 1);  // zeros + everyone resident

  float* outH = out + (size_t)B_ * T_ * H_;

  for (int s = 1; s <= T_; ++s) {
    const int src = (s - 1) & 1, dst = s & 1;
    const short* Ahi = hbuf + (size_t)src * HN;
    const short* Alo = hbuf + (size_t)(2 + src) * HN;
    short* Dhi = hbuf + (size_t)dst * HN;
    short* Dlo = hbuf + (size_t)(2 + dst) * HN;

    const int mA0 = wv * 32 + lm;  // A row for row-tile 0 (tile 1 = +16)
    const short* pa0h = Ahi + (size_t)mA0 * H_ + lq * 8;
    const short* pa0l = Alo + (size_t)mA0 * H_ + lq * 8;
    const short* pa1h = pa0h + 16 * H_;
    const short* pa1l = pa0l + 16 * H_;

    f32x4 z = {0.f, 0.f, 0.f, 0.f};
    f32x4 a00 = z, a01 = z, a02 = z, a10 = z, a11 = z, a12 = z;
#pragma unroll 4
    for (int kb = 0; kb < 32; ++kb) {
      bf16x8 ah0 = *(const bf16x8*)(pa0h + kb * 32);
      bf16x8 al0 = *(const bf16x8*)(pa0l + kb * 32);
      bf16x8 ah1 = *(const bf16x8*)(pa1h + kb * 32);
      bf16x8 al1 = *(const bf16x8*)(pa1l + kb * 32);
      bf16x8 bfh = *(const bf16x8*)&BhiS[(kb * 64 + lane) * 8];
      bf16x8 bfl = *(const bf16x8*)&BloS[(kb * 64 + lane) * 8];
      a00 = __builtin_amdgcn_mfma_f32_16x16x32_bf16(ah0, bfh, a00, 0, 0, 0);
      a01 = __builtin_amdgcn_mfma_f32_16x16x32_bf16(ah0, bfl, a01, 0, 0, 0);
      a02 = __builtin_amdgcn_mfma_f32_16x16x32_bf16(al0, bfh, a02, 0, 0, 0);
      a10 = __builtin_amdgcn_mfma_f32_16x16x32_bf16(ah1, bfh, a10, 0, 0, 0);
      a11 = __builtin_amdgcn_mfma_f32_16x16x32_bf16(ah1, bfl, a11, 0, 0, 0);
      a12 = __builtin_amdgcn_mfma_f32_16x16x32_bf16(al1, bfh, a12, 0, 0, 0);
    }
    f32x4 r0 = a00 + a01 + a02;
    f32x4 r1 = a10 + a11 + a12;

    const int t = s - 1;
    const int rb = wv * 32 + lq * 4;  // C-frag row base (tile 0)
    const int n = n0 + lm;
#pragma unroll
    for (int r = 0; r < 4; ++r) {
      {
        const int b = rb + r;
        const size_t oidx = (size_t)b * (T_ * H_) + (size_t)t * H_ + n;
        float v = out[oidx] + r0[r];
        v = v > 0.f ? v : 0.f;
        out[oidx] = v;
        const short hv = f2bf(v);
        Dhi[b * H_ + n] = hv;
        Dlo[b * H_ + n] = f2bf(v - bf2f(hv));
        if (s == T_) outH[b * H_ + n] = v;
      }
      {
        const int b = rb + 16 + r;
        const size_t oidx = (size_t)b * (T_ * H_) + (size_t)t * H_ + n;
        float v = out[oidx] + r1[r];
        v = v > 0.f ? v : 0.f;
        out[oidx] = v;
        const short hv = f2bf(v);
        Dhi[b * H_ + n] = hv;
        Dlo[b * H_ + n] = f2bf(v - bf2f(hv));
        if (s == T_) outH[b * H_ + n] = v;
      }
    }
    if (s < T_) grid_barrier(flags, g, tid, s + 1);
  }
}

// ---------------------------------------------------------------------------
extern "C" void kernel_launch(void* const* d_in, const int* in_sizes, int n_in,
                              void* d_out, int out_size, void* d_ws,
                              size_t ws_size, hipStream_t stream) {
  const float* x = (const float*)d_in[0];   // [B,T,I]
  const float* Wi = (const float*)d_in[1];  // [H,I]
  const float* bi = (const float*)d_in[2];  // [H]
  const float* Wh = (const float*)d_in[3];  // [H,H]
  const float* bh = (const float*)d_in[4];  // [H]
  float* out = (float*)d_out;

  int* flags = (int*)d_ws;                              // 64*16 ints = 4 KB
  short* hbuf = (short*)((char*)d_ws + G_ * FPAD * 4);  // 4 x 128 KB hi/lo ping-pong

  // pre -> d_out in place (row m = b*T + t maps to out offset m*H)
  proj_gemm<<<2048, 256, 0, stream>>>(x, Wi, bi, bh, out);
  // persistent sequential recurrence
  rnn_rec<<<G_, 128, 0, stream>>>(Wh, out, hbuf, flags);
}

// Round 2
// 9075.616 us; speedup vs baseline: 1.5386x; 1.5386x over previous
//
#include <hip/hip_runtime.h>

#define B_ 64
#define T_ 512
#define I_ 512
#define H_ 1024
#define HN (B_ * H_)   // elements per h plane (interleaved hi|lo uints)
#define FPAD 16        // flags padded to 64B lines
#define G_ 64          // recurrence workgroups

typedef __attribute__((ext_vector_type(8))) short bf16x8;
typedef __attribute__((ext_vector_type(4))) float f32x4;

static __device__ __forceinline__ short f2bf(float f) {
  unsigned u = __float_as_uint(f);
  unsigned r = (u + 0x7fffu + ((u >> 16) & 1u)) >> 16;  // RNE
  return (short)(unsigned short)r;
}
static __device__ __forceinline__ float bf2f(short s) {
  return __uint_as_float(((unsigned)(unsigned short)s) << 16);
}
static __device__ __forceinline__ bf16x8 pack8(float4 u, float4 v) {
  bf16x8 r;
  r[0] = f2bf(u.x); r[1] = f2bf(u.y); r[2] = f2bf(u.z); r[3] = f2bf(u.w);
  r[4] = f2bf(v.x); r[5] = f2bf(v.y); r[6] = f2bf(v.z); r[7] = f2bf(v.w);
  return r;
}

// ---------------------------------------------------------------------------
// Kernel 1 (unchanged from R1): pre = x @ Wi^T + bi + bh, in-place into d_out.
// ---------------------------------------------------------------------------
#define PBK 32
#define PLDA 40

__global__ __launch_bounds__(256) void proj_gemm(
    const float* __restrict__ x, const float* __restrict__ Wi,
    const float* __restrict__ bi, const float* __restrict__ bh,
    float* __restrict__ out) {
  __shared__ short As[128 * PLDA];
  __shared__ short Bs[128 * PLDA];
  const int tid = threadIdx.x;
  const int m0 = (blockIdx.x >> 3) * 128;
  const int n0 = (blockIdx.x & 7) * 128;
  const int wave = tid >> 6, lane = tid & 63;
  const int wm = (wave & 1) * 64, wn = (wave >> 1) * 64;
  const int lm = lane & 15, lq = lane >> 4;

  f32x4 acc[4][4];
#pragma unroll
  for (int i = 0; i < 4; ++i)
#pragma unroll
    for (int j = 0; j < 4; ++j) {
      f32x4 z = {0.f, 0.f, 0.f, 0.f};
      acc[i][j] = z;
    }

  const int lrow = tid >> 1;
  const int lcol = (tid & 1) * 16;
  const float* xp = x + (size_t)(m0 + lrow) * I_ + lcol;
  const float* wp = Wi + (size_t)(n0 + lrow) * I_ + lcol;

  for (int k0 = 0; k0 < I_; k0 += PBK) {
    float4 a0 = *(const float4*)(xp + k0);
    float4 a1 = *(const float4*)(xp + k0 + 4);
    float4 a2 = *(const float4*)(xp + k0 + 8);
    float4 a3 = *(const float4*)(xp + k0 + 12);
    float4 b0 = *(const float4*)(wp + k0);
    float4 b1 = *(const float4*)(wp + k0 + 4);
    float4 b2 = *(const float4*)(wp + k0 + 8);
    float4 b3 = *(const float4*)(wp + k0 + 12);
    __syncthreads();
    *(bf16x8*)&As[lrow * PLDA + lcol] = pack8(a0, a1);
    *(bf16x8*)&As[lrow * PLDA + lcol + 8] = pack8(a2, a3);
    *(bf16x8*)&Bs[lrow * PLDA + lcol] = pack8(b0, b1);
    *(bf16x8*)&Bs[lrow * PLDA + lcol + 8] = pack8(b2, b3);
    __syncthreads();

    bf16x8 af[4], bfr[4];
#pragma unroll
    for (int i = 0; i < 4; ++i)
      af[i] = *(const bf16x8*)&As[(wm + i * 16 + lm) * PLDA + lq * 8];
#pragma unroll
    for (int j = 0; j < 4; ++j)
      bfr[j] = *(const bf16x8*)&Bs[(wn + j * 16 + lm) * PLDA + lq * 8];
#pragma unroll
    for (int i = 0; i < 4; ++i)
#pragma unroll
      for (int j = 0; j < 4; ++j)
        acc[i][j] = __builtin_amdgcn_mfma_f32_16x16x32_bf16(af[i], bfr[j],
                                                            acc[i][j], 0, 0, 0);
  }

  const int rb = m0 + wm + lq * 4;
  const int cb = n0 + wn + lm;
#pragma unroll
  for (int j = 0; j < 4; ++j) {
    const int n = cb + j * 16;
    const float bias = bi[n] + bh[n];
#pragma unroll
    for (int i = 0; i < 4; ++i) {
      const int m = rb + i * 16;
#pragma unroll
      for (int r = 0; r < 4; ++r)
        out[(size_t)(m + r) * H_ + n] = acc[i][j][r] + bias;
    }
  }
}

// ---------------------------------------------------------------------------
// Agent-scope (device-coherent, L2-bypassing sc1) access helpers. No fences:
// sc1 ops go straight to L3 which IS device-coherent; s_waitcnt vmcnt(0)
// before the flag store provides release ordering.
// ---------------------------------------------------------------------------
static __device__ __forceinline__ unsigned long long ld_a8(const void* p) {
  return __hip_atomic_load((const unsigned long long*)p, __ATOMIC_RELAXED,
                           __HIP_MEMORY_SCOPE_AGENT);
}
static __device__ __forceinline__ void st_a4(unsigned* p, unsigned v) {
  __hip_atomic_store(p, v, __ATOMIC_RELAXED, __HIP_MEMORY_SCOPE_AGENT);
}

// Barrier among G_ WGs: per-wave vmcnt drain -> syncthreads -> flag store;
// wave 0 polls all 64 flags (one per lane); ws poison 0xAA = negative ints,
// so "wait until >= val" needs no flag init.
static __device__ __forceinline__ void gbar(int* flags, int g, int tid,
                                            int val) {
  asm volatile("s_waitcnt vmcnt(0)" ::: "memory");  // own sc1 stores at L3
  __syncthreads();
  if (tid == 0)
    __hip_atomic_store(&flags[g * FPAD], val, __ATOMIC_RELAXED,
                       __HIP_MEMORY_SCOPE_AGENT);
  if (tid < 64) {
    while (__hip_atomic_load(&flags[tid * FPAD], __ATOMIC_RELAXED,
                             __HIP_MEMORY_SCOPE_AGENT) < val) {}
  }
  __syncthreads();
}

// ---------------------------------------------------------------------------
// Kernel 2: persistent recurrence. 64 WGs x 256 threads (4 waves, 16 rows
// each). WG g owns cols [16g,16g+16). Wh-hi bf16 in VGPRs (128/lane,
// replicated per wave), Wh-lo bf16 in LDS (32 KB, B-frag order). h exchanged
// via interleaved (hi | lo<<16) uints with agent-scope atomics (sc1, L3
// coherent) -- NO threadfence/L2-flush anywhere. Depth-8 register pipeline
// covers L3 load latency.
// ---------------------------------------------------------------------------
__global__ __launch_bounds__(256, 1) void rnn_rec(
    const float* __restrict__ Wh, float* __restrict__ out,
    unsigned* __restrict__ hbuf, int* __restrict__ flags) {
  __shared__ short BloS[32 * 64 * 8];  // 32 KB
  const int tid = threadIdx.x;
  const int g = blockIdx.x;
  const int n0 = g * 16;
  const int wv = tid >> 6;   // 0..3
  const int lane = tid & 63;
  const int lm = lane & 15, lq = lane >> 4;
  const int r0 = wv * 16;    // this wave's 16 batch rows

  // --- init: Wh-hi frags into regs (all waves), Wh-lo into LDS (wave 0) ---
  bf16x8 bh[32];
  const float* wrow = Wh + (size_t)(n0 + lm) * H_ + lq * 8;
#pragma unroll
  for (int kb = 0; kb < 32; ++kb) {
    float4 w0 = *(const float4*)(wrow + kb * 32);
    float4 w1 = *(const float4*)(wrow + kb * 32 + 4);
    float wf[8] = {w0.x, w0.y, w0.z, w0.w, w1.x, w1.y, w1.z, w1.w};
    bf16x8 hi;
#pragma unroll
    for (int j = 0; j < 8; ++j) hi[j] = f2bf(wf[j]);
    bh[kb] = hi;
    if (wv == 0) {
#pragma unroll
      for (int j = 0; j < 8; ++j)
        BloS[(kb * 64 + lane) * 8 + j] = f2bf(wf[j] - bf2f(hi[j]));
    }
  }

  // --- zero h0 (ping plane 0), this WG's columns, device-coherent ---
  for (int i = tid; i < B_ * 16; i += 256) {
    const int b = i >> 4, c = n0 + (i & 15);
    st_a4(&hbuf[(size_t)b * H_ + c], 0u);
  }

  gbar(flags, g, tid, 1);  // zeros visible + LDS staged + all resident

  float* outH = out + (size_t)B_ * T_ * H_;
  const f32x4 z = {0.f, 0.f, 0.f, 0.f};

  for (int s = 1; s <= T_; ++s) {
    const unsigned* src = hbuf + (size_t)((s - 1) & 1) * HN;
    unsigned* dst = hbuf + (size_t)(s & 1) * HN;
    // lane's A stream: row r0+lm, elements kb*32 + lq*8 .. +8 (32B per kb)
    const char* pa =
        (const char*)(src + (size_t)(r0 + lm) * H_ + lq * 8);

    unsigned long long pq[8][4];  // depth-8 in-flight buffer (32B/slot)
#pragma unroll
    for (int kb = 0; kb < 8; ++kb) {
      const char* p = pa + kb * 128;
      pq[kb][0] = ld_a8(p);
      pq[kb][1] = ld_a8(p + 8);
      pq[kb][2] = ld_a8(p + 16);
      pq[kb][3] = ld_a8(p + 24);
    }

    f32x4 c0 = z, c1 = z, c2 = z;
#pragma unroll
    for (int kb = 0; kb < 32; ++kb) {
      bf16x8 ah, al;
#pragma unroll
      for (int qq = 0; qq < 4; ++qq) {
        const unsigned lo32 = (unsigned)pq[kb & 7][qq];
        const unsigned hi32 = (unsigned)(pq[kb & 7][qq] >> 32);
        ah[2 * qq] = (short)(lo32 & 0xffffu);
        al[2 * qq] = (short)(lo32 >> 16);
        ah[2 * qq + 1] = (short)(hi32 & 0xffffu);
        al[2 * qq + 1] = (short)(hi32 >> 16);
      }
      const bf16x8 bl = *(const bf16x8*)&BloS[(kb * 64 + lane) * 8];
      c0 = __builtin_amdgcn_mfma_f32_16x16x32_bf16(ah, bh[kb], c0, 0, 0, 0);
      c1 = __builtin_amdgcn_mfma_f32_16x16x32_bf16(ah, bl, c1, 0, 0, 0);
      c2 = __builtin_amdgcn_mfma_f32_16x16x32_bf16(al, bh[kb], c2, 0, 0, 0);
      if (kb + 8 < 32) {
        const char* p = pa + (kb + 8) * 128;
        pq[kb & 7][0] = ld_a8(p);
        pq[kb & 7][1] = ld_a8(p + 8);
        pq[kb & 7][2] = ld_a8(p + 16);
        pq[kb & 7][3] = ld_a8(p + 24);
      }
    }
    const f32x4 rsum = c0 + c1 + c2;

    const int t = s - 1;
    const int n = n0 + lm;
#pragma unroll
    for (int r = 0; r < 4; ++r) {
      const int b = r0 + lq * 4 + r;
      const size_t oidx = (size_t)b * (T_ * H_) + (size_t)t * H_ + n;
      float v = out[oidx] + rsum[r];
      v = v > 0.f ? v : 0.f;
      out[oidx] = v;
      const short hv = f2bf(v);
      const short lv = f2bf(v - bf2f(hv));
      st_a4(&dst[(size_t)b * H_ + n],
            (unsigned)(unsigned short)hv |
                ((unsigned)(unsigned short)lv << 16));
      if (s == T_) outH[(size_t)b * H_ + n] = v;
    }
    if (s < T_) gbar(flags, g, tid, s + 1);
  }
}

// ---------------------------------------------------------------------------
extern "C" void kernel_launch(void* const* d_in, const int* in_sizes, int n_in,
                              void* d_out, int out_size, void* d_ws,
                              size_t ws_size, hipStream_t stream) {
  const float* x = (const float*)d_in[0];   // [B,T,I]
  const float* Wi = (const float*)d_in[1];  // [H,I]
  const float* bi = (const float*)d_in[2];  // [H]
  const float* Wh = (const float*)d_in[3];  // [H,H]
  const float* bh = (const float*)d_in[4];  // [H]
  float* out = (float*)d_out;

  int* flags = (int*)d_ws;                               // 64*16 ints = 4 KB
  unsigned* hbuf = (unsigned*)((char*)d_ws + G_ * FPAD * 4);  // 2 planes x 256 KB

  proj_gemm<<<2048, 256, 0, stream>>>(x, Wi, bi, bh, out);
  rnn_rec<<<G_, 256, 0, stream>>>(Wh, out, hbuf, flags);
}

// Round 3
// 4211.607 us; speedup vs baseline: 3.3154x; 2.1549x over previous
//
#include <hip/hip_runtime.h>

#define B_ 64
#define T_ 512
#define I_ 512
#define H_ 1024
#define PLANE 65536   // uints per h plane (B_*H_), fragment-major packed hi|lo
#define FPAD 16       // flag padding: 16 ints = 64 B line
#define NWAVE 256     // 64 WGs x 4 waves -> per-wave flags
#define G_ 64

typedef __attribute__((ext_vector_type(8))) short bf16x8;
typedef __attribute__((ext_vector_type(4))) float f32x4;

static __device__ __forceinline__ short f2bf(float f) {
  unsigned u = __float_as_uint(f);
  unsigned r = (u + 0x7fffu + ((u >> 16) & 1u)) >> 16;  // RNE
  return (short)(unsigned short)r;
}
static __device__ __forceinline__ float bf2f(short s) {
  return __uint_as_float(((unsigned)(unsigned short)s) << 16);
}
static __device__ __forceinline__ bf16x8 pack8(float4 u, float4 v) {
  bf16x8 r;
  r[0] = f2bf(u.x); r[1] = f2bf(u.y); r[2] = f2bf(u.z); r[3] = f2bf(u.w);
  r[4] = f2bf(v.x); r[5] = f2bf(v.y); r[6] = f2bf(v.z); r[7] = f2bf(v.w);
  return r;
}

// ---------------------------------------------------------------------------
// Kernel 1 (unchanged): pre = x @ Wi^T + bi + bh, in-place into d_out.
// ---------------------------------------------------------------------------
#define PBK 32
#define PLDA 40

__global__ __launch_bounds__(256) void proj_gemm(
    const float* __restrict__ x, const float* __restrict__ Wi,
    const float* __restrict__ bi, const float* __restrict__ bh,
    float* __restrict__ out) {
  __shared__ short As[128 * PLDA];
  __shared__ short Bs[128 * PLDA];
  const int tid = threadIdx.x;
  const int m0 = (blockIdx.x >> 3) * 128;
  const int n0 = (blockIdx.x & 7) * 128;
  const int wave = tid >> 6, lane = tid & 63;
  const int wm = (wave & 1) * 64, wn = (wave >> 1) * 64;
  const int lm = lane & 15, lq = lane >> 4;

  f32x4 acc[4][4];
#pragma unroll
  for (int i = 0; i < 4; ++i)
#pragma unroll
    for (int j = 0; j < 4; ++j) {
      f32x4 z = {0.f, 0.f, 0.f, 0.f};
      acc[i][j] = z;
    }

  const int lrow = tid >> 1;
  const int lcol = (tid & 1) * 16;
  const float* xp = x + (size_t)(m0 + lrow) * I_ + lcol;
  const float* wp = Wi + (size_t)(n0 + lrow) * I_ + lcol;

  for (int k0 = 0; k0 < I_; k0 += PBK) {
    float4 a0 = *(const float4*)(xp + k0);
    float4 a1 = *(const float4*)(xp + k0 + 4);
    float4 a2 = *(const float4*)(xp + k0 + 8);
    float4 a3 = *(const float4*)(xp + k0 + 12);
    float4 b0 = *(const float4*)(wp + k0);
    float4 b1 = *(const float4*)(wp + k0 + 4);
    float4 b2 = *(const float4*)(wp + k0 + 8);
    float4 b3 = *(const float4*)(wp + k0 + 12);
    __syncthreads();
    *(bf16x8*)&As[lrow * PLDA + lcol] = pack8(a0, a1);
    *(bf16x8*)&As[lrow * PLDA + lcol + 8] = pack8(a2, a3);
    *(bf16x8*)&Bs[lrow * PLDA + lcol] = pack8(b0, b1);
    *(bf16x8*)&Bs[lrow * PLDA + lcol + 8] = pack8(b2, b3);
    __syncthreads();

    bf16x8 af[4], bfr[4];
#pragma unroll
    for (int i = 0; i < 4; ++i)
      af[i] = *(const bf16x8*)&As[(wm + i * 16 + lm) * PLDA + lq * 8];
#pragma unroll
    for (int j = 0; j < 4; ++j)
      bfr[j] = *(const bf16x8*)&Bs[(wn + j * 16 + lm) * PLDA + lq * 8];
#pragma unroll
    for (int i = 0; i < 4; ++i)
#pragma unroll
      for (int j = 0; j < 4; ++j)
        acc[i][j] = __builtin_amdgcn_mfma_f32_16x16x32_bf16(af[i], bfr[j],
                                                            acc[i][j], 0, 0, 0);
  }

  const int rb = m0 + wm + lq * 4;
  const int cb = n0 + wn + lm;
#pragma unroll
  for (int j = 0; j < 4; ++j) {
    const int n = cb + j * 16;
    const float bias = bi[n] + bh[n];
#pragma unroll
    for (int i = 0; i < 4; ++i) {
      const int m = rb + i * 16;
#pragma unroll
      for (int r = 0; r < 4; ++r)
        out[(size_t)(m + r) * H_ + n] = acc[i][j][r] + bias;
    }
  }
}

// ---------------------------------------------------------------------------
// Agent-scope (L3-coherent, L2-bypassing) helpers.
// ---------------------------------------------------------------------------
static __device__ __forceinline__ unsigned long long ld_a8(const void* p) {
  return __hip_atomic_load((const unsigned long long*)p, __ATOMIC_RELAXED,
                           __HIP_MEMORY_SCOPE_AGENT);
}
static __device__ __forceinline__ void st_a4(unsigned* p, unsigned v) {
  __hip_atomic_store(p, v, __ATOMIC_RELAXED, __HIP_MEMORY_SCOPE_AGENT);
}
static __device__ __forceinline__ int ld_flag(const int* p) {
  return __hip_atomic_load(p, __ATOMIC_RELAXED, __HIP_MEMORY_SCOPE_AGENT);
}

// ---------------------------------------------------------------------------
// Kernel 2: persistent recurrence, fragment-major h exchange.
//
// h plane layout (uint = bf16 hi | lo<<16): element (b,n) with
//   wv=b>>4, lm=b&15, kb=n>>5, lq=(n>>3)&3, j=n&7, c=j>>1, L=lq*16+lm:
//   U(b,n) = (kb*4+wv)*512 + c*128 + L*2 + (j&1)
// => consumer wave wv at K-block kb issues 4 ld_a8 at byte offsets
//    (kb*4+wv)*2048 + c*512 + lane*8   -- 64 lanes x 8 B fully dense.
//
// Sync: per-WAVE flags. aflag[w]=s means wave w's h_s slice is at L3
// (store -> s_waitcnt vmcnt(0) -> flag). Each wave independently polls all
// 256 flags >= s-1 before reading h_{s-1}; no __syncthreads in the loop.
// Ping-pong is safe: passing wait-all(s-1) proves every wave's step-(s-1)
// A-loads retired (they precede that wave's vmcnt(0)+flag).
// ---------------------------------------------------------------------------
__global__ __launch_bounds__(256, 1) void rnn_rec(
    const float* __restrict__ Wh, float* __restrict__ out,
    unsigned* __restrict__ planes, int* __restrict__ aflag) {
  __shared__ short BhiS[2048 * 8];  // 32 KB, B-frag order
  __shared__ short BloS[2048 * 8];  // 32 KB
  const int tid = threadIdx.x;
  const int g = blockIdx.x;
  const int n0 = g * 16;
  const int wv = tid >> 6;   // 0..3  (= consumer row-group AND producer b>>4)
  const int lane = tid & 63;
  const int lm = lane & 15, lq = lane >> 4;

  // --- stage Wh hi/lo into LDS in exact B-frag order ---
  for (int idx = tid; idx < 2048; idx += 256) {
    const int kb = idx >> 6, l = idx & 63;
    const int n = n0 + (l & 15);
    const int k = kb * 32 + (l >> 4) * 8;
    const float* p = Wh + (size_t)n * H_ + k;
    float4 w0 = *(const float4*)p;
    float4 w1 = *(const float4*)(p + 4);
    float wf[8] = {w0.x, w0.y, w0.z, w0.w, w1.x, w1.y, w1.z, w1.w};
#pragma unroll
    for (int j = 0; j < 8; ++j) {
      const short h = f2bf(wf[j]);
      BhiS[idx * 8 + j] = h;
      BloS[idx * 8 + j] = f2bf(wf[j] - bf2f(h));
    }
  }
  __syncthreads();

  // --- producer-side address constants (this thread owns (b,np), b=wv*16+lq*4+r) ---
  const int np = n0 + lm;
  const int kbp = np >> 5, lqp = (np >> 3) & 3, jp = np & 7;
  const int Ubase = (kbp * 4 + wv) * 512 + (jp >> 1) * 128 + lqp * 32 + (jp & 1);
  // U(b) = Ubase + (lq*4+r)*2

  // --- h_0 = 0 into plane 0; per-wave flag = 0 ---
#pragma unroll
  for (int r = 0; r < 4; ++r) st_a4(&planes[Ubase + (lq * 4 + r) * 2], 0u);
  asm volatile("s_waitcnt vmcnt(0)" ::: "memory");
  if (lane == 0)
    __hip_atomic_store(&aflag[(g * 4 + wv) * FPAD], 0, __ATOMIC_RELAXED,
                       __HIP_MEMORY_SCOPE_AGENT);

  float* outH = out + (size_t)B_ * T_ * H_;
  const f32x4 z = {0.f, 0.f, 0.f, 0.f};

  for (int s = 1; s <= T_; ++s) {
    const int t = s - 1;
    // prefetch pre values (independent of flags; overlaps the poll)
    size_t oidx[4];
    float pre[4];
#pragma unroll
    for (int r = 0; r < 4; ++r) {
      const int b = wv * 16 + lq * 4 + r;
      oidx[r] = (size_t)b * (T_ * H_) + (size_t)t * H_ + np;
      pre[r] = out[oidx[r]];
    }

    // wait-all: each lane polls 4 wave-flags (256 total per wave)
    const int need = s - 1;
    for (;;) {
      const int f0 = ld_flag(&aflag[(lane * 4 + 0) * FPAD]);
      const int f1 = ld_flag(&aflag[(lane * 4 + 1) * FPAD]);
      const int f2 = ld_flag(&aflag[(lane * 4 + 2) * FPAD]);
      const int f3 = ld_flag(&aflag[(lane * 4 + 3) * FPAD]);
      if (f0 >= need && f1 >= need && f2 >= need && f3 >= need) break;
    }

    const char* src = (const char*)(planes + (size_t)((s - 1) & 1) * PLANE);
    unsigned* dst = planes + (size_t)(s & 1) * PLANE;

    // 16-deep dense A-load pipeline: block kb, chunk c at byte
    //   (kb*4+wv)*2048 + c*512 + lane*8
    unsigned long long pq[16][4];
#pragma unroll
    for (int k2 = 0; k2 < 16; ++k2) {
      const char* p = src + ((size_t)(k2 * 4 + wv) * 2048) + lane * 8;
      pq[k2][0] = ld_a8(p);
      pq[k2][1] = ld_a8(p + 512);
      pq[k2][2] = ld_a8(p + 1024);
      pq[k2][3] = ld_a8(p + 1536);
    }

    f32x4 c0 = z, c1 = z, c2 = z;
#pragma unroll
    for (int kb = 0; kb < 32; ++kb) {
      const int sl = kb & 15;
      bf16x8 ah, al;
#pragma unroll
      for (int c = 0; c < 4; ++c) {
        const unsigned u0 = (unsigned)pq[sl][c];
        const unsigned u1 = (unsigned)(pq[sl][c] >> 32);
        ah[2 * c] = (short)(u0 & 0xffffu);
        al[2 * c] = (short)(u0 >> 16);
        ah[2 * c + 1] = (short)(u1 & 0xffffu);
        al[2 * c + 1] = (short)(u1 >> 16);
      }
      const bf16x8 bh = *(const bf16x8*)&BhiS[(kb * 64 + lane) * 8];
      const bf16x8 bl = *(const bf16x8*)&BloS[(kb * 64 + lane) * 8];
      c0 = __builtin_amdgcn_mfma_f32_16x16x32_bf16(ah, bh, c0, 0, 0, 0);
      c1 = __builtin_amdgcn_mfma_f32_16x16x32_bf16(ah, bl, c1, 0, 0, 0);
      c2 = __builtin_amdgcn_mfma_f32_16x16x32_bf16(al, bh, c2, 0, 0, 0);
      if (kb + 16 < 32) {
        const char* p = src + ((size_t)((kb + 16) * 4 + wv) * 2048) + lane * 8;
        pq[sl][0] = ld_a8(p);
        pq[sl][1] = ld_a8(p + 512);
        pq[sl][2] = ld_a8(p + 1024);
        pq[sl][3] = ld_a8(p + 1536);
      }
    }
    const f32x4 rs = c0 + c1 + c2;

    // epilogue: h-plane stores FIRST (critical chain), then flag, then out
    float v[4];
#pragma unroll
    for (int r = 0; r < 4; ++r) {
      float vv = pre[r] + rs[r];
      vv = vv > 0.f ? vv : 0.f;
      v[r] = vv;
      const short hv = f2bf(vv);
      const short lv = f2bf(vv - bf2f(hv));
      st_a4(&dst[Ubase + (lq * 4 + r) * 2],
            (unsigned)(unsigned short)hv | ((unsigned)(unsigned short)lv << 16));
    }
    asm volatile("s_waitcnt vmcnt(0)" ::: "memory");  // h slice at L3
    if (lane == 0)
      __hip_atomic_store(&aflag[(g * 4 + wv) * FPAD], s, __ATOMIC_RELAXED,
                         __HIP_MEMORY_SCOPE_AGENT);
    // out writes off the critical chain (WG-private)
#pragma unroll
    for (int r = 0; r < 4; ++r) {
      out[oidx[r]] = v[r];
      if (s == T_) outH[(size_t)(wv * 16 + lq * 4 + r) * H_ + np] = v[r];
    }
  }
}

// ---------------------------------------------------------------------------
extern "C" void kernel_launch(void* const* d_in, const int* in_sizes, int n_in,
                              void* d_out, int out_size, void* d_ws,
                              size_t ws_size, hipStream_t stream) {
  const float* x = (const float*)d_in[0];   // [B,T,I]
  const float* Wi = (const float*)d_in[1];  // [H,I]
  const float* bi = (const float*)d_in[2];  // [H]
  const float* Wh = (const float*)d_in[3];  // [H,H]
  const float* bh = (const float*)d_in[4];  // [H]
  float* out = (float*)d_out;

  int* aflag = (int*)d_ws;  // 256 wave-flags x 64 B = 16 KB
  unsigned* planes = (unsigned*)((char*)d_ws + NWAVE * FPAD * 4);  // 2 x 256 KB

  proj_gemm<<<2048, 256, 0, stream>>>(x, Wi, bi, bh, out);
  rnn_rec<<<G_, 256, 0, stream>>>(Wh, out, planes, aflag);
}